// Round 13
// baseline (52.845 us; speedup 1.0000x reference)
//
#include <hip/hip_runtime.h>

namespace {
constexpr int N_ELEMS = 262144;
constexpr int N_NODES = 263169;
constexpr int N_UNITS = N_ELEMS * 4;          // 1048576 (e, ip) units
constexpr int BLK     = 256;
constexpr int GRID1   = 1024;                 // gather_pack blocks (4/CU)
constexpr int GRID2   = 1024;                 // stream_energy blocks (4/CU)

// ws layout (floats): packed element records, then partials
constexpr long long WSP_F    = 12LL * N_ELEMS;          // 3.1M floats = 12.58 MB
constexpr long long P2_OFF   = WSP_F;                   // 2*GRID2 floats
constexpr long long PI_OFF   = P2_OFF + 2LL * GRID2;    // GRID1 floats

// folded material constants (fp32, match reference math)
constexpr float GC_2L0  = 0.09f;
constexpr float L0SQ    = 0.015f * 0.015f;
constexpr float MU_     = 80.76923076923077f;
constexpr float K_MOD   = 175.0f;
constexpr float PENALTY = 1799.82f;
}

typedef float vfloat4 __attribute__((ext_vector_type(4)));

__device__ __forceinline__ float waveReduce(float x) {
#pragma unroll
    for (int off = 32; off; off >>= 1) x += __shfl_down(x, off, 64);
    return x;
}

// ---------------------------------------------------------------------------
// Phase 1: gather c/u/v per (element, node-slot) into packed 48B/element
// records; also the nodal irreversibility penalty. Grid-stride, no barriers
// until the final block reduction.
// ---------------------------------------------------------------------------
__global__ __launch_bounds__(256) void gather_pack(
    const float* __restrict__ u, const float* __restrict__ v,
    const float* __restrict__ c, const float* __restrict__ prev_c,
    const int* __restrict__ conn,
    float* __restrict__ wsP, float* __restrict__ partialsI)
{
    const int t0 = blockIdx.x * BLK + threadIdx.x;
    const int stride = GRID1 * BLK;

    float Eirr = 0.f;
    for (int n = t0; n < N_NODES; n += stride) {
        const float d = fmaxf(prev_c[n] - c[n], 0.f);
        Eirr += 0.5f * PENALTY * d * d;
    }

    for (int w = t0; w < N_UNITS; w += stride) {
        const int e  = w >> 2;
        const int ip = w & 3;
        const int idx = conn[w];               // lane-linear index load
        wsP[12 * e + ip]     = c[idx];         // gathers hit ~1MB L2-resident
        wsP[12 * e + 4 + ip] = u[idx];
        wsP[12 * e + 8 + ip] = v[idx];
    }

    Eirr = waveReduce(Eirr);
    __shared__ float sI[4];
    const int lane = threadIdx.x & 63, wid = threadIdx.x >> 6;
    if (lane == 0) sI[wid] = Eirr;
    __syncthreads();
    if (threadIdx.x == 0)
        partialsI[blockIdx.x] = sI[0] + sI[1] + sI[2] + sI[3];
}

// ---------------------------------------------------------------------------
// Phase 2: calib-shaped streaming energy. Grid-stride loop, zero indirection,
// zero barriers/LDS/shuffles in the loop. All loads lane-linear or quad-dense.
// ---------------------------------------------------------------------------
__global__ __launch_bounds__(256) void stream_energy(
    const float* __restrict__ wsP,
    const float* __restrict__ Nf, const float* __restrict__ dNdx,
    const float* __restrict__ B, const float* __restrict__ vol,
    float* __restrict__ partials)
{
    const vfloat4* W   = reinterpret_cast<const vfloat4*>(wsP);
    const vfloat4* Nf4 = reinterpret_cast<const vfloat4*>(Nf);
    const vfloat4* Df4 = reinterpret_cast<const vfloat4*>(dNdx);
    const vfloat4* Bf4 = reinterpret_cast<const vfloat4*>(B);

    float Eel = 0.f, Efr = 0.f;

    // N_UNITS == 4 * GRID2 * BLK exactly -> 4 iterations, no tail
    for (int unit = blockIdx.x * BLK + threadIdx.x; unit < N_UNITS;
         unit += GRID2 * BLK) {
        const int e = unit >> 2;

        const vfloat4 cv = W[3 * e];          // c0..c3 (quad-broadcast, dense)
        const vfloat4 uv = W[3 * e + 1];      // u0..u3
        const vfloat4 vv = W[3 * e + 2];      // v0..v3
        const vfloat4 Nr = Nf4[unit];         // lane-linear
        const vfloat4 dx = Df4[2 * unit];     // pair-linear
        const vfloat4 dy = Df4[2 * unit + 1];
        const long long b6 = 6LL * unit;      // 6-stride dense
        const vfloat4 b0 = Bf4[b6 + 0], b1 = Bf4[b6 + 1], b2 = Bf4[b6 + 2];
        const vfloat4 b3 = Bf4[b6 + 3], b4 = Bf4[b6 + 4], b5 = Bf4[b6 + 5];
        const float  vip = vol[unit];         // lane-linear

        const float o0 = 1.f - cv.x, o1 = 1.f - cv.y;
        const float o2 = 1.f - cv.z, o3 = 1.f - cv.w;
        const float omc = Nr.x * o0 + Nr.y * o1 + Nr.z * o2 + Nr.w * o3;
        const float g   = omc * omc;
        const float cip = 1.f - omc;
        const float gx  = dx.x * cv.x + dx.y * cv.y + dx.z * cv.z + dx.w * cv.w;
        const float gy  = dy.x * cv.x + dy.y * cv.y + dy.z * cv.z + dy.w * cv.w;
        Efr += GC_2L0 * (cip * cip + L0SQ * (gx * gx + gy * gy)) * vip;

        const float exx = b0.x * uv.x + b0.y * vv.x + b0.z * uv.y + b0.w * vv.y
                        + b1.x * uv.z + b1.y * vv.z + b1.z * uv.w + b1.w * vv.w;
        const float eyy = b2.x * uv.x + b2.y * vv.x + b2.z * uv.y + b2.w * vv.y
                        + b3.x * uv.z + b3.y * vv.z + b3.z * uv.w + b3.w * vv.w;
        const float gxy = b4.x * uv.x + b4.y * vv.x + b4.z * uv.y + b4.w * vv.y
                        + b5.x * uv.z + b5.y * vv.z + b5.z * uv.w + b5.w * vv.w;
        const float exy = 0.5f * gxy;
        const float tr  = exx + eyy, tr3 = tr * (1.f / 3.f);
        const float dxx = exx - tr3, dyy = eyy - tr3, dzz = -tr3;
        const float dev2 = dxx * dxx + dyy * dyy + dzz * dzz + 2.f * exy * exy;
        const float trp = fmaxf(tr, 0.f), trn = fminf(tr, 0.f);
        Eel += ((0.5f * K_MOD * trp * trp + MU_ * dev2) * g
                + 0.5f * K_MOD * trn * trn) * vip;
    }

    Eel = waveReduce(Eel);
    Efr = waveReduce(Efr);
    __shared__ float sE[4], sF[4];
    const int lane = threadIdx.x & 63, wid = threadIdx.x >> 6;
    if (lane == 0) { sE[wid] = Eel; sF[wid] = Efr; }
    __syncthreads();
    if (threadIdx.x == 0) {
        float* p = partials + 2ll * blockIdx.x;
        p[0] = sE[0] + sE[1] + sE[2] + sE[3];
        p[1] = sF[0] + sF[1] + sF[2] + sF[3];
    }
}

__global__ __launch_bounds__(256) void final_reduce(
    const float* __restrict__ partials, const float* __restrict__ partialsI,
    float* __restrict__ out)
{
    float s0 = 0.f, s1 = 0.f, s2 = 0.f;
    for (int i = threadIdx.x; i < GRID2; i += 256) {
        s0 += partials[2ll * i];
        s1 += partials[2ll * i + 1];
    }
    for (int i = threadIdx.x; i < GRID1; i += 256)
        s2 += partialsI[i];
    s0 = waveReduce(s0);
    s1 = waveReduce(s1);
    s2 = waveReduce(s2);
    __shared__ float sA[4], sB[4], sC[4];
    const int lane = threadIdx.x & 63, wid = threadIdx.x >> 6;
    if (lane == 0) { sA[wid] = s0; sB[wid] = s1; sC[wid] = s2; }
    __syncthreads();
    if (threadIdx.x == 0) {
        out[0] = sA[0] + sA[1] + sA[2] + sA[3];
        out[1] = sB[0] + sB[1] + sB[2] + sB[3];
        out[2] = sC[0] + sC[1] + sC[2] + sC[3];
    }
}

extern "C" void kernel_launch(void* const* d_in, const int* in_sizes, int n_in,
                              void* d_out, int out_size, void* d_ws, size_t ws_size,
                              hipStream_t stream) {
    const float* u      = (const float*)d_in[0];
    const float* v      = (const float*)d_in[1];
    const float* c      = (const float*)d_in[2];
    const float* prev_c = (const float*)d_in[3];
    const int*   conn   = (const int*)d_in[4];
    const float* Nf     = (const float*)d_in[5];
    const float* dNdx   = (const float*)d_in[6];
    const float* B      = (const float*)d_in[7];
    const float* vol    = (const float*)d_in[8];
    float* out = (float*)d_out;

    float* wsP       = (float*)d_ws;          // 12.58 MB packed records
    float* partials  = wsP + P2_OFF;          // 2*1024 floats
    float* partialsI = wsP + PI_OFF;          // 1024 floats

    gather_pack<<<GRID1, BLK, 0, stream>>>(u, v, c, prev_c, conn, wsP, partialsI);
    stream_energy<<<GRID2, BLK, 0, stream>>>(wsP, Nf, dNdx, B, vol, partials);
    final_reduce<<<1, BLK, 0, stream>>>(partials, partialsI, out);
}